// Round 3
// baseline (1034.869 us; speedup 1.0000x reference)
//
#include <hip/hip_runtime.h>
#include <hip/hip_bf16.h>

#define NID  16
#define BB   4
#define HH   192
#define WW   192
#define DHW  1179648          // 32*192*192
#define KB   256              // lovasz buckets over e in [0,2]

#define C1   1152             // pass1 blocks per batch
#define CH1  1024             // voxels per pass1 block
#define C3   288              // pass3 blocks per batch
#define CH3  4096             // voxels per pass3 block

// workspace layout (float indices)
#define WS_STATS 0            // [64][8]: cnt, sx, sy, sz, s0, s1, s2, ssq
#define WS_FIN   512          // [64][8]: cx, cy, cz, e0, e1, e2, var, exists
#define WS_BG    1024         // [4]
#define WS_SEEDB 1028         // [4]
#define WS_INSTL 1032         // [64]
#define WS_HIST  1104         // [64][2][KB] floats: cntF, cntB
#define WS_TOTAL (1104 + 64*2*KB)

__device__ __forceinline__ float ftanh(float x) {
    float t = __expf(2.f * x);
    return 1.f - 2.f / (t + 1.f);
}
__device__ __forceinline__ float fsigmoid(float x) {
    return 1.f / (1.f + __expf(-x));
}
// xyzm is a linspace stack: compute from flat index. W=192 divisible by 4, so
// a float4 group shares (h,d) and has w = w0..w0+3.
__device__ __forceinline__ void xyz_of4(int v, float& x0, float& y, float& z) {
    int w = v % WW;
    int t = v / WW;
    int h = t % HH;
    int d = t / HH;
    x0 = (float)w * (1.f / 191.f);
    y  = (float)h * (1.f / 191.f);
    z  = (float)d * (1.f / 31.f);
}

// ---- pass 1: per-(b,id) masked stats via register accumulators ----
// Wave w of each block handles ids [4w+1, 4w+4]; scans the whole chunk.
__global__ __launch_bounds__(256) void pass1_stats(
    const float* __restrict__ pred, const int* __restrict__ inst,
    const int* __restrict__ labels, float* __restrict__ ws)
{
    const int b = blockIdx.y, tid = threadIdx.x;
    const int wv = tid >> 6, lane = tid & 63;
    const int id0 = wv * 4 + 1;

    const float* p3 = pred + (size_t)(b * 7 + 3) * DHW;
    const float4* s0p = (const float4*)p3;
    const float4* s1p = (const float4*)(p3 + DHW);
    const float4* s2p = (const float4*)(p3 + 2 * DHW);
    const float4* slp = (const float4*)(p3 + 3 * DHW);
    const int4* ibp = (const int4*)(inst + (size_t)b * DHW);
    const int4* lbp = (const int4*)(labels + (size_t)b * DHW);

    float acc[4][8];
    #pragma unroll
    for (int q = 0; q < 4; ++q)
        #pragma unroll
        for (int s = 0; s < 8; ++s) acc[q][s] = 0.f;

    const int f40 = (blockIdx.x * CH1) >> 2;   // 256 f4 per block
    for (int it = 0; it < 4; ++it) {
        const int fi = f40 + it * 64 + lane;
        const float4 s0 = s0p[fi], s1 = s1p[fi], s2 = s2p[fi];
        const int4 id4 = ibp[fi];
        const float* a0 = &s0.x; const float* a1 = &s1.x; const float* a2 = &s2.x;
        const int* ida = &id4.x;
        float x0, y, z; xyz_of4(fi * 4, x0, y, z);
        #pragma unroll
        for (int vv = 0; vv < 4; ++vv) {
            const float u0 = a0[vv], u1 = a1[vv], u2 = a2[vv];
            const float sq = u0 * u0 + u1 * u1 + u2 * u2;
            const float x = x0 + (float)vv * (1.f / 191.f);
            const int id = ida[vv];
            #pragma unroll
            for (int q = 0; q < 4; ++q) {
                const float bs = (id == id0 + q) ? 1.f : 0.f;
                acc[q][0] += bs;      acc[q][1] += bs * x;
                acc[q][2] += bs * y;  acc[q][3] += bs * z;
                acc[q][4] += bs * u0; acc[q][5] += bs * u1;
                acc[q][6] += bs * u2; acc[q][7] += bs * sq;
            }
        }
    }
    // bg seed: each wave handles its private quarter of the chunk
    float bg = 0.f;
    {
        const int fi = f40 + wv * 64 + lane;
        const float4 sl = slp[fi];
        const int4 l4 = lbp[fi];
        const float* sa = &sl.x; const int* la = &l4.x;
        #pragma unroll
        for (int vv = 0; vv < 4; ++vv) {
            const float sd = fsigmoid(sa[vv]);
            if (la[vv] == 0) bg += sd * sd;
        }
    }
    // wave shuffle-reduce, then lane 0 -> global atomics
    #pragma unroll
    for (int q = 0; q < 4; ++q)
        #pragma unroll
        for (int s = 0; s < 8; ++s) {
            float v = acc[q][s];
            for (int off = 32; off > 0; off >>= 1) v += __shfl_down(v, off, 64);
            acc[q][s] = v;
        }
    for (int off = 32; off > 0; off >>= 1) bg += __shfl_down(bg, off, 64);
    if (lane == 0) {
        #pragma unroll
        for (int q = 0; q < 4; ++q)
            #pragma unroll
            for (int s = 0; s < 8; ++s)
                if (acc[q][s] != 0.f)
                    atomicAdd(&ws[WS_STATS + (b * NID + wv * 4 + q) * 8 + s], acc[q][s]);
        if (bg != 0.f) atomicAdd(&ws[WS_BG + b], bg);
    }
}

// ---------------- pass 2: finalize per-(b,id) stats ----------------
__global__ void pass2_fin(float* __restrict__ ws)
{
    const int t = threadIdx.x;
    if (t >= 64) return;
    const float* s = ws + WS_STATS + t * 8;
    const float cnt = s[0];
    const float exists = (cnt > 0.f) ? 1.f : 0.f;
    const float safe = fmaxf(cnt, 1.f);
    const float m0 = s[4] / safe, m1 = s[5] / safe, m2 = s[6] / safe;
    float* f = ws + WS_FIN + t * 8;
    f[0] = s[1] / safe; f[1] = s[2] / safe; f[2] = s[3] / safe;
    f[3] = __expf(10.f * m0); f[4] = __expf(10.f * m1); f[5] = __expf(10.f * m2);
    f[6] = (s[7] - cnt * (m0 * m0 + m1 * m1 + m2 * m2)) / (3.f * safe);
    f[7] = exists;
}

// ---- pass 3: register-resident voxels, count-only LDS histograms ----
__global__ __launch_bounds__(256) void pass3_hist(
    const float* __restrict__ pred, const int* __restrict__ inst,
    float* __restrict__ ws)
{
    __shared__ unsigned cntFB[NID][KB];   // 16 KB: lo16 FG count, hi16 BG count
    __shared__ float ctrs[NID][6];        // cx,cy,cz,e0,e1,e2
    __shared__ float sred[4];

    const int b = blockIdx.y, tid = threadIdx.x;

    for (int i = tid; i < NID * KB; i += 256) ((unsigned*)cntFB)[i] = 0u;
    if (tid < NID * 6) {
        const int iid = tid / 6, j = tid % 6;
        ctrs[iid][j] = ws[WS_FIN + (b * NID + iid) * 8 + j];
    }
    __syncthreads();

    const float* pb = pred + (size_t)b * 7 * DHW;
    const float4* t0 = (const float4*)pb;
    const float4* t1 = (const float4*)(pb + DHW);
    const float4* t2 = (const float4*)(pb + 2 * DHW);
    const float4* sp = (const float4*)(pb + 6 * DHW);
    const int4* ibp = (const int4*)(inst + (size_t)b * DHW);

    float sacc = 0.f;
    const int f40 = (blockIdx.x * CH3) >> 2;   // 1024 f4 per block
    for (int it = 0; it < 4; ++it) {
        const int fi = f40 + it * 256 + tid;
        const float4 a = t0[fi], c = t1[fi], d = t2[fi], sl = sp[fi];
        const int4 id4 = ibp[fi];
        const float* aa = &a.x; const float* ca = &c.x;
        const float* da = &d.x; const float* sa = &sl.x;
        const int* ida = &id4.x;
        float x0, y, z; xyz_of4(fi * 4, x0, y, z);

        float se0[4], se1[4], se2[4], sdv[4];
        #pragma unroll
        for (int vv = 0; vv < 4; ++vv) {
            se0[vv] = ftanh(aa[vv]) + x0 + (float)vv * (1.f / 191.f);
            se1[vv] = ftanh(ca[vv]) + y;
            se2[vv] = ftanh(da[vv]) + z;
            sdv[vv] = fsigmoid(sa[vv]);
        }
        #pragma unroll
        for (int g = 0; g < 4; ++g) {
            float cx[4], cy[4], cz[4], e0[4], e1[4], e2[4];
            #pragma unroll
            for (int q = 0; q < 4; ++q) {
                const int iid = g * 4 + q;
                cx[q] = ctrs[iid][0]; cy[q] = ctrs[iid][1]; cz[q] = ctrs[iid][2];
                e0[q] = ctrs[iid][3]; e1[q] = ctrs[iid][4]; e2[q] = ctrs[iid][5];
            }
            #pragma unroll
            for (int vv = 0; vv < 4; ++vv) {
                const int id = ida[vv];
                #pragma unroll
                for (int q = 0; q < 4; ++q) {
                    const int iid = g * 4 + q;
                    const float d0 = se0[vv] - cx[q];
                    const float d1 = se1[vv] - cy[q];
                    const float d2 = se2[vv] - cz[q];
                    const float q2 = d0 * d0 * e0[q] + d1 * d1 * e1[q] + d2 * d2 * e2[q];
                    const float dist = __expf(-q2);
                    const bool m = (id == iid + 1);
                    const float e = m ? (2.f - 2.f * dist) : (2.f * dist);
                    int k = (int)(e * 128.f);
                    k = min(max(k, 0), KB - 1);
                    // BG in bucket 0 contributes exactly 0 -> skip its atomic.
                    const unsigned val = m ? 1u : (k ? 0x10000u : 0u);
                    if (m) { const float ds = sdv[vv] - dist; sacc += ds * ds; }
                    if (val) atomicAdd(&cntFB[iid][k], val);
                }
            }
        }
    }
    __syncthreads();

    // merge packed LDS counts -> global float histograms (zero-skip).
    // Nonexistent-instance garbage is harmless: pass4 gates on `exists`.
    float* gh = ws + WS_HIST;
    for (int i = tid; i < NID * KB; i += 256) {
        const int iid = i >> 8, k = i & (KB - 1);
        const unsigned c = cntFB[iid][k];
        float* basep = gh + (size_t)(b * NID + iid) * 2 * KB;
        const float cf = (float)(c & 0xFFFFu);
        const float cb = (float)(c >> 16);
        if (cf != 0.f) atomicAdd(&basep[k], cf);
        if (cb != 0.f) atomicAdd(&basep[KB + k], cb);
    }
    // per-batch seed loss reduce
    float v = sacc;
    for (int off = 32; off > 0; off >>= 1) v += __shfl_down(v, off, 64);
    if ((tid & 63) == 0) sred[tid >> 6] = v;
    __syncthreads();
    if (tid == 0) atomicAdd(&ws[WS_SEEDB + b], sred[0] + sred[1] + sred[2] + sred[3]);
}

// ---- pass 4: lovasz from count histograms (midpoint e) ----
__global__ __launch_bounds__(256) void pass4_lovasz(float* __restrict__ ws)
{
    const int t = blockIdx.x;    // (b*16 + iid)
    const int j = threadIdx.x;   // j=0 <-> highest-error bucket
    __shared__ float sF[KB], sB[KB];
    __shared__ double red[KB];

    const float P = ws[WS_STATS + t * 8];
    const float exists = ws[WS_FIN + t * 8 + 7];
    const float* gh = ws + WS_HIST + (size_t)t * 2 * KB;

    const int k = KB - 1 - j;
    const float nF = gh[k], nB = gh[KB + k];
    const float mid = ((float)k + 0.5f) * (1.f / 128.f);
    const float rF = nF * mid, rB = nB * mid;

    sF[j] = nF; sB[j] = nB;
    __syncthreads();
    for (int off = 1; off < KB; off <<= 1) {
        float a = 0.f, c = 0.f;
        if (j >= off) { a = sF[j - off]; c = sB[j - off]; }
        __syncthreads();
        sF[j] += a; sB[j] += c;
        __syncthreads();
    }
    double contrib = 0.0;
    if (exists != 0.f && P > 0.f) {
        const double Bb = (double)sB[j] - (double)nB;
        const double U0 = (double)P + Bb;
        const double Fafter = (double)sF[j];
        contrib = (double)rF / U0
                + (double)rB * ((double)P - Fafter) / (U0 * (U0 + (double)nB));
    }
    red[j] = contrib;
    __syncthreads();
    for (int off = KB / 2; off > 0; off >>= 1) {
        if (j < off) red[j] += red[j + off];
        __syncthreads();
    }
    if (j == 0) ws[WS_INSTL + t] = (float)red[0];
}

// ---------------- pass 5: final assembly ----------------
__global__ void pass5_final(const float* __restrict__ ws, float* __restrict__ out)
{
    const int t = threadIdx.x;
    __shared__ float ex[64], vv[64], il[64];
    if (t < 64) {
        ex[t] = ws[WS_FIN + t * 8 + 7];
        vv[t] = ws[WS_FIN + t * 8 + 6] * ex[t];
        il[t] = ws[WS_INSTL + t];
    }
    __syncthreads();
    if (t == 0) {
        float linst = 0.f, lvar = 0.f, lseed = 0.f;
        for (int b = 0; b < BB; ++b) {
            float obj = 0.f, v = 0.f, i2 = 0.f;
            for (int i = 0; i < NID; ++i) {
                const int u = b * NID + i;
                obj += ex[u]; v += vv[u]; i2 += il[u];
            }
            const float denom = fmaxf(obj, 1.f);
            linst += i2 / denom;
            lvar  += v / denom;
            lseed += (ws[WS_SEEDB + b] + ws[WS_BG + b]) / (float)DHW;
        }
        linst *= 1.0f / BB;
        lvar  *= 10.0f / BB;
        lseed *= 1.0f / BB;
        out[0] = linst;
        out[1] = lvar;
        out[2] = lseed;
        out[3] = linst + lvar + lseed;
    }
}

extern "C" void kernel_launch(void* const* d_in, const int* in_sizes, int n_in,
                              void* d_out, int out_size, void* d_ws, size_t ws_size,
                              hipStream_t stream)
{
    const float* pred   = (const float*)d_in[0];
    const int*   inst   = (const int*)  d_in[1];
    const int*   labels = (const int*)  d_in[2];
    // d_in[3] = center_images (unused), d_in[4] = xyzm (computed analytically)
    float* ws  = (float*)d_ws;
    float* out = (float*)d_out;

    hipMemsetAsync(d_ws, 0, (size_t)WS_TOTAL * sizeof(float), stream);

    pass1_stats<<<dim3(C1, BB), 256, 0, stream>>>(pred, inst, labels, ws);
    pass2_fin  <<<1, 64, 0, stream>>>(ws);
    pass3_hist <<<dim3(C3, BB), 256, 0, stream>>>(pred, inst, ws);
    pass4_lovasz<<<64, KB, 0, stream>>>(ws);
    pass5_final<<<1, 64, 0, stream>>>(ws, out);
}

// Round 5
// 482.256 us; speedup vs baseline: 2.1459x; 2.1459x over previous
//
#include <hip/hip_runtime.h>
#include <hip/hip_bf16.h>

#define NID  16
#define BB   4
#define HH   192
#define WW   192
#define DHW  1179648          // 32*192*192
#define KB   256              // lovasz buckets over e in [0,2]

#define NBLK1 288             // pass1 blocks per batch
#define CHV1  4096            // voxels per pass1 block
#define NBLK3 288             // pass3 blocks per batch
#define CHV3  4096            // voxels per pass3 block

// workspace layout (float indices)
#define WS_STATS 0            // [64][8]: cnt, sx, sy, sz, s0, s1, s2, ssq
#define WS_FIN   512          // [64][8]: cx, cy, cz, e0, e1, e2, var, exists
#define WS_BG    1024         // [4]
#define WS_SEEDB 1028         // [4]
#define WS_INSTL 1032         // [64]
#define WS_HIST  1104         // [64][2][KB] floats: cntF, cntB
#define WS_TOTAL (1104 + 64*2*KB)

__device__ __forceinline__ float ftanh(float x) {
    float t = __expf(2.f * x);
    return 1.f - 2.f / (t + 1.f);
}
__device__ __forceinline__ float fsigmoid(float x) {
    return 1.f / (1.f + __expf(-x));
}
// xyzm is a linspace stack: compute from flat index. W=192 divisible by 4, so
// a float4 group shares (h,d) and has w = w0..w0+3.
__device__ __forceinline__ void xyz_of4(int v, float& x0, float& y, float& z) {
    int w = v % WW;
    int t = v / WW;
    int h = t % HH;
    int d = t / HH;
    x0 = (float)w * (1.f / 191.f);
    y  = (float)h * (1.f / 191.f);
    z  = (float)d * (1.f / 31.f);
}

// ---- pass 1: per-(b,id) masked stats, NAMED-SCALAR register accumulators ----
// Wave w handles ids [4w+1, 4w+4]; each wave scans the whole 4096-voxel chunk.
// No local arrays, no address-taken vector components (scratch-spill pathology
// in R3: VGPR=40 + 19MB WRITE_SIZE = accumulators in scratch).
#define ACCD(Q) float aC##Q=0.f, aX##Q=0.f, aY##Q=0.f, aZ##Q=0.f, aU##Q=0.f, aV##Q=0.f, aW##Q=0.f, aR##Q=0.f;
#define UPD(Q) { const float bs = (idv == id0 + Q) ? 1.f : 0.f; \
    aC##Q += bs;                 aX##Q = fmaf(bs, xx, aX##Q); \
    aY##Q = fmaf(bs, yy, aY##Q); aZ##Q = fmaf(bs, zz, aZ##Q); \
    aU##Q = fmaf(bs, u0, aU##Q); aV##Q = fmaf(bs, u1, aV##Q); \
    aW##Q = fmaf(bs, u2, aW##Q); aR##Q = fmaf(bs, sq, aR##Q); }
#define VOX(U0,U1,U2,IDV,XO) { \
    const float u0=(U0), u1=(U1), u2=(U2); const int idv=(IDV); \
    const float sq = u0*u0 + u1*u1 + u2*u2; const float xx = x0 + (XO); \
    UPD(0) UPD(1) UPD(2) UPD(3) }
#define WR(V) { V += __shfl_down(V,32,64); V += __shfl_down(V,16,64); \
    V += __shfl_down(V,8,64); V += __shfl_down(V,4,64); \
    V += __shfl_down(V,2,64); V += __shfl_down(V,1,64); }
#define WR8(Q) WR(aC##Q) WR(aX##Q) WR(aY##Q) WR(aZ##Q) WR(aU##Q) WR(aV##Q) WR(aW##Q) WR(aR##Q)
#define ST(Q) if (aC##Q != 0.f) { \
    float* dp = ws + WS_STATS + (size_t)(b * NID + id0 - 1 + Q) * 8; \
    atomicAdd(dp+0, aC##Q); atomicAdd(dp+1, aX##Q); atomicAdd(dp+2, aY##Q); atomicAdd(dp+3, aZ##Q); \
    atomicAdd(dp+4, aU##Q); atomicAdd(dp+5, aV##Q); atomicAdd(dp+6, aW##Q); atomicAdd(dp+7, aR##Q); }
#define BGV(S,L) { const float s_ = fsigmoid(S); if ((L) == 0) bg = fmaf(s_, s_, bg); }

__global__ __launch_bounds__(256) void pass1_stats(
    const float* __restrict__ pred, const int* __restrict__ inst,
    const int* __restrict__ labels, float* __restrict__ ws)
{
    const int b = blockIdx.y, tid = threadIdx.x;
    const int wv = tid >> 6, lane = tid & 63;
    const int id0 = wv * 4 + 1;

    const float* p3 = pred + (size_t)(b * 7 + 3) * DHW;
    const float4* s0p = (const float4*)p3;
    const float4* s1p = (const float4*)(p3 + DHW);
    const float4* s2p = (const float4*)(p3 + 2 * DHW);
    const float4* slp = (const float4*)(p3 + 3 * DHW);
    const int4* ibp = (const int4*)(inst + (size_t)b * DHW);
    const int4* lbp = (const int4*)(labels + (size_t)b * DHW);

    ACCD(0) ACCD(1) ACCD(2) ACCD(3)

    const int f40 = (blockIdx.x * CHV1) >> 2;   // 1024 f4 per block
    for (int it = 0; it < 16; ++it) {
        const int fi = f40 + it * 64 + lane;
        const float4 s0 = s0p[fi], s1 = s1p[fi], s2 = s2p[fi];
        const int4 id4 = ibp[fi];
        float x0, yy, zz; xyz_of4(fi * 4, x0, yy, zz);
        VOX(s0.x, s1.x, s2.x, id4.x, 0.f)
        VOX(s0.y, s1.y, s2.y, id4.y, 1.f / 191.f)
        VOX(s0.z, s1.z, s2.z, id4.z, 2.f / 191.f)
        VOX(s0.w, s1.w, s2.w, id4.w, 3.f / 191.f)
    }
    // bg seed: each wave handles its private quarter of the chunk
    float bg = 0.f;
    for (int it = 0; it < 4; ++it) {
        const int fi = f40 + (wv * 4 + it) * 64 + lane;
        const float4 sl = slp[fi];
        const int4 l4 = lbp[fi];
        BGV(sl.x, l4.x) BGV(sl.y, l4.y) BGV(sl.z, l4.z) BGV(sl.w, l4.w)
    }

    WR8(0) WR8(1) WR8(2) WR8(3) WR(bg)
    if (lane == 0) {
        ST(0) ST(1) ST(2) ST(3)
        if (bg != 0.f) atomicAdd(&ws[WS_BG + b], bg);
    }
}

// ---------------- pass 2: finalize per-(b,id) stats ----------------
__global__ void pass2_fin(float* __restrict__ ws)
{
    const int t = threadIdx.x;
    if (t >= 64) return;
    const float* s = ws + WS_STATS + t * 8;
    const float cnt = s[0];
    const float exists = (cnt > 0.f) ? 1.f : 0.f;
    const float safe = fmaxf(cnt, 1.f);
    const float m0 = s[4] / safe, m1 = s[5] / safe, m2 = s[6] / safe;
    float* f = ws + WS_FIN + t * 8;
    f[0] = s[1] / safe; f[1] = s[2] / safe; f[2] = s[3] / safe;
    f[3] = __expf(10.f * m0); f[4] = __expf(10.f * m1); f[5] = __expf(10.f * m2);
    f[6] = (s[7] - cnt * (m0 * m0 + m1 * m1 + m2 * m2)) / (3.f * safe);
    f[7] = exists;
}

// ---- pass 3: register-resident voxels, float4 LDS ctr broadcasts ----
#define INST(SEX,SEY,SEZ,SD,IDV) { \
    const float d0 = (SEX) - ua.x; const float d1 = (SEY) - ua.y; const float d2 = (SEZ) - ua.z; \
    const float q2 = d0*d0*ua.w + d1*d1*ub.x + d2*d2*ub.y; \
    const float dist = __expf(-q2); \
    const bool m = ((IDV) == gi + 1); \
    const float e = m ? (2.f - 2.f*dist) : (2.f*dist); \
    int k = (int)(e * 128.f); k = min(max(k, 0), KB - 1); \
    const unsigned val = m ? 1u : (k ? 0x10000u : 0u); \
    if (m) { const float ds = (SD) - dist; sacc = fmaf(ds, ds, sacc); } \
    if (val) atomicAdd(&cntFB[gi][k], val); }

__global__ __launch_bounds__(256) void pass3_hist(
    const float* __restrict__ pred, const int* __restrict__ inst,
    float* __restrict__ ws)
{
    __shared__ unsigned cntFB[NID][KB];   // 16 KB: lo16 FG count, hi16 BG count
    __shared__ float4 ctr4[NID][2];       // {cx,cy,cz,e0},{e1,e2,var,exists}
    __shared__ float sred[4];

    const int b = blockIdx.y, tid = threadIdx.x;

    for (int i = tid; i < NID * KB; i += 256) ((unsigned*)cntFB)[i] = 0u;
    if (tid < NID * 2)
        ((float4*)ctr4)[tid] = ((const float4*)(ws + WS_FIN + (size_t)b * NID * 8))[tid];
    __syncthreads();

    const float* pb = pred + (size_t)b * 7 * DHW;
    const float4* t0 = (const float4*)pb;
    const float4* t1 = (const float4*)(pb + DHW);
    const float4* t2 = (const float4*)(pb + 2 * DHW);
    const float4* sp = (const float4*)(pb + 6 * DHW);
    const int4* ibp = (const int4*)(inst + (size_t)b * DHW);

    float sacc = 0.f;
    const int f40 = (blockIdx.x * CHV3) >> 2;   // 1024 f4 per block
    for (int it = 0; it < 4; ++it) {
        const int fi = f40 + it * 256 + tid;
        const float4 a = t0[fi], c = t1[fi], d = t2[fi], sl = sp[fi];
        const int4 id4 = ibp[fi];
        float x0, y, z; xyz_of4(fi * 4, x0, y, z);

        const float sx0 = ftanh(a.x) + x0;
        const float sx1 = ftanh(a.y) + x0 + 1.f / 191.f;
        const float sx2 = ftanh(a.z) + x0 + 2.f / 191.f;
        const float sx3 = ftanh(a.w) + x0 + 3.f / 191.f;
        const float sy0 = ftanh(c.x) + y, sy1 = ftanh(c.y) + y;
        const float sy2 = ftanh(c.z) + y, sy3 = ftanh(c.w) + y;
        const float sz0 = ftanh(d.x) + z, sz1 = ftanh(d.y) + z;
        const float sz2 = ftanh(d.z) + z, sz3 = ftanh(d.w) + z;
        const float sd0 = fsigmoid(sl.x), sd1 = fsigmoid(sl.y);
        const float sd2 = fsigmoid(sl.z), sd3 = fsigmoid(sl.w);

        #pragma unroll
        for (int gi = 0; gi < NID; ++gi) {
            const float4 ua = ctr4[gi][0];
            const float4 ub = ctr4[gi][1];
            if (ub.w == 0.f) continue;     // nonexistent instance (uniform)
            INST(sx0, sy0, sz0, sd0, id4.x)
            INST(sx1, sy1, sz1, sd1, id4.y)
            INST(sx2, sy2, sz2, sd2, id4.z)
            INST(sx3, sy3, sz3, sd3, id4.w)
        }
    }
    __syncthreads();

    // merge packed LDS counts -> global float histograms (zero-skip)
    float* gh = ws + WS_HIST;
    for (int i = tid; i < NID * KB; i += 256) {
        const int iid = i >> 8, k = i & (KB - 1);
        const unsigned cc = cntFB[iid][k];
        float* basep = gh + (size_t)(b * NID + iid) * 2 * KB;
        const float cf = (float)(cc & 0xFFFFu);
        const float cb = (float)(cc >> 16);
        if (cf != 0.f) atomicAdd(&basep[k], cf);
        if (cb != 0.f) atomicAdd(&basep[KB + k], cb);
    }
    // per-batch seed loss reduce
    float v = sacc;
    WR(v)
    if ((tid & 63) == 0) sred[tid >> 6] = v;
    __syncthreads();
    if (tid == 0) atomicAdd(&ws[WS_SEEDB + b], sred[0] + sred[1] + sred[2] + sred[3]);
}

// ---- pass 4: lovasz from count histograms (midpoint e) ----
__global__ __launch_bounds__(256) void pass4_lovasz(float* __restrict__ ws)
{
    const int t = blockIdx.x;    // (b*16 + iid)
    const int j = threadIdx.x;   // j=0 <-> highest-error bucket
    __shared__ float sF[KB], sB[KB];
    __shared__ double red[KB];

    const float P = ws[WS_STATS + t * 8];
    const float exists = ws[WS_FIN + t * 8 + 7];
    const float* gh = ws + WS_HIST + (size_t)t * 2 * KB;

    const int k = KB - 1 - j;
    const float nF = gh[k], nB = gh[KB + k];
    const float mid = ((float)k + 0.5f) * (1.f / 128.f);
    const float rF = nF * mid, rB = nB * mid;

    sF[j] = nF; sB[j] = nB;
    __syncthreads();
    for (int off = 1; off < KB; off <<= 1) {
        float a = 0.f, c = 0.f;
        if (j >= off) { a = sF[j - off]; c = sB[j - off]; }
        __syncthreads();
        sF[j] += a; sB[j] += c;
        __syncthreads();
    }
    double contrib = 0.0;
    if (exists != 0.f && P > 0.f) {
        const double Bb = (double)sB[j] - (double)nB;
        const double U0 = (double)P + Bb;
        const double Fafter = (double)sF[j];
        contrib = (double)rF / U0
                + (double)rB * ((double)P - Fafter) / (U0 * (U0 + (double)nB));
    }
    red[j] = contrib;
    __syncthreads();
    for (int off = KB / 2; off > 0; off >>= 1) {
        if (j < off) red[j] += red[j + off];
        __syncthreads();
    }
    if (j == 0) ws[WS_INSTL + t] = (float)red[0];
}

// ---------------- pass 5: final assembly ----------------
__global__ void pass5_final(const float* __restrict__ ws, float* __restrict__ out)
{
    const int t = threadIdx.x;
    __shared__ float ex[64], vv[64], il[64];
    if (t < 64) {
        ex[t] = ws[WS_FIN + t * 8 + 7];
        vv[t] = ws[WS_FIN + t * 8 + 6] * ex[t];
        il[t] = ws[WS_INSTL + t];
    }
    __syncthreads();
    if (t == 0) {
        float linst = 0.f, lvar = 0.f, lseed = 0.f;
        for (int b = 0; b < BB; ++b) {
            float obj = 0.f, v = 0.f, i2 = 0.f;
            for (int i = 0; i < NID; ++i) {
                const int u = b * NID + i;
                obj += ex[u]; v += vv[u]; i2 += il[u];
            }
            const float denom = fmaxf(obj, 1.f);
            linst += i2 / denom;
            lvar  += v / denom;
            lseed += (ws[WS_SEEDB + b] + ws[WS_BG + b]) / (float)DHW;
        }
        linst *= 1.0f / BB;
        lvar  *= 10.0f / BB;
        lseed *= 1.0f / BB;
        out[0] = linst;
        out[1] = lvar;
        out[2] = lseed;
        out[3] = linst + lvar + lseed;
    }
}

extern "C" void kernel_launch(void* const* d_in, const int* in_sizes, int n_in,
                              void* d_out, int out_size, void* d_ws, size_t ws_size,
                              hipStream_t stream)
{
    const float* pred   = (const float*)d_in[0];
    const int*   inst   = (const int*)  d_in[1];
    const int*   labels = (const int*)  d_in[2];
    // d_in[3] = center_images (unused), d_in[4] = xyzm (computed analytically)
    float* ws  = (float*)d_ws;
    float* out = (float*)d_out;

    hipMemsetAsync(d_ws, 0, (size_t)WS_TOTAL * sizeof(float), stream);

    pass1_stats<<<dim3(NBLK1, BB), 256, 0, stream>>>(pred, inst, labels, ws);
    pass2_fin  <<<1, 64, 0, stream>>>(ws);
    pass3_hist <<<dim3(NBLK3, BB), 256, 0, stream>>>(pred, inst, ws);
    pass4_lovasz<<<64, KB, 0, stream>>>(ws);
    pass5_final<<<1, 64, 0, stream>>>(ws, out);
}